// Round 3
// baseline (225.209 us; speedup 1.0000x reference)
//
#include <hip/hip_runtime.h>

#define BLOCK 256
#define TILE  1024   // gaussians per block (4 per thread)

typedef float f4 __attribute__((ext_vector_type(4)));   // nontemporal-builtin-friendly

__global__ __launch_bounds__(BLOCK) void gauss_cov_kernel(
    const float4* __restrict__ quat,
    const float4* __restrict__ lsc4,   // log_scale viewed as float4
    f4*           __restrict__ out4,   // covariance viewed as float4
    int n)
{
    __shared__ float smf[TILE * 9];    // 36 KB; reused for ls stage then out stage
    float4* sm4 = (float4*)smf;
    f4*     smv = (f4*)smf;

    const int tid = threadIdx.x;
    const int g0  = blockIdx.x * TILE;

    // ---- stage log_scale: 3*TILE floats = 768 float4, fully coalesced ----
    const int nls4   = (3 * n) / 4;        // 3N floats, N multiple of 4 -> exact
    const int lbase4 = (3 * g0) / 4;       // 768 * blockIdx.x (g0 % 4 == 0)
    #pragma unroll
    for (int k = 0; k < 3; ++k) {
        const int idx = k * BLOCK + tid;   // 0..767
        const int gi  = lbase4 + idx;
        if (gi < nls4) sm4[idx] = lsc4[gi];
    }
    __syncthreads();

    // read this thread's 4 gaussians' log_scales (stride-3 dwords: <=2-way, free)
    float ls[4][3];
    #pragma unroll
    for (int k = 0; k < 4; ++k) {
        const int gl = k * BLOCK + tid;
        ls[k][0] = smf[3 * gl + 0];
        ls[k][1] = smf[3 * gl + 1];
        ls[k][2] = smf[3 * gl + 2];
    }
    __syncthreads();   // ls region about to be overwritten by out staging

    // ---- compute + stage covariance into LDS ----
    #pragma unroll
    for (int k = 0; k < 4; ++k) {
        const int gl = k * BLOCK + tid;
        const int g  = g0 + gl;
        if (g < n) {
            const float4 q4 = quat[g];
            const float dot  = q4.x * q4.x + q4.y * q4.y + q4.z * q4.z + q4.w * q4.w;
            const float inv  = 1.0f / fmaxf(sqrtf(dot), 1e-12f);
            const float qw = q4.x * inv;
            const float qx = q4.y * inv;
            const float qy = q4.z * inv;
            const float qz = q4.w * inv;

            const float r00 = 1.f - 2.f * (qy * qy + qz * qz);
            const float r01 = 2.f * (qx * qy - qz * qw);
            const float r02 = 2.f * (qx * qz + qy * qw);
            const float r10 = 2.f * (qx * qy + qz * qw);
            const float r11 = 1.f - 2.f * (qx * qx + qz * qz);
            const float r12 = 2.f * (qy * qz - qx * qw);
            const float r20 = 2.f * (qx * qz - qy * qw);
            const float r21 = 2.f * (qy * qz + qx * qw);
            const float r22 = 1.f - 2.f * (qx * qx + qy * qy);

            const float s0 = expf(ls[k][0]);
            const float s1 = expf(ls[k][1]);
            const float s2 = expf(ls[k][2]);

            float c[9];
            c[0] = s0 * r00 * r00 + s1 * r01 * r01 + s2 * r02 * r02;
            c[1] = s0 * r00 * r10 + s1 * r01 * r11 + s2 * r02 * r12;
            c[2] = s0 * r00 * r20 + s1 * r01 * r21 + s2 * r02 * r22;
            c[3] = c[1];
            c[4] = s0 * r10 * r10 + s1 * r11 * r11 + s2 * r12 * r12;
            c[5] = s0 * r10 * r20 + s1 * r11 * r21 + s2 * r12 * r22;
            c[6] = c[2];
            c[7] = c[5];
            c[8] = s0 * r20 * r20 + s1 * r21 * r21 + s2 * r22 * r22;

            #pragma unroll
            for (int j = 0; j < 9; ++j)
                smf[gl * 9 + j] = c[j];    // stride-9 dwords: <=2-way, free
        }
    }
    __syncthreads();

    // ---- store: 9*TILE floats = 2304 float4 per block, 9 per thread ----
    const int nout4  = (9 * n) / 4;        // 9e6
    const int obase4 = (9 * g0) / 4;       // 2304 * blockIdx.x
    #pragma unroll
    for (int k = 0; k < 9; ++k) {
        const int idx = k * BLOCK + tid;   // 0..2303
        const int gi  = obase4 + idx;
        if (gi < nout4) {
            const f4 v = smv[idx];         // ds_read_b128, conflict-free
            __builtin_nontemporal_store(v, &out4[gi]);
        }
    }
}

extern "C" void kernel_launch(void* const* d_in, const int* in_sizes, int n_in,
                              void* d_out, int out_size, void* d_ws, size_t ws_size,
                              hipStream_t stream) {
    const float4* quat = (const float4*)d_in[0];
    const float4* lsc4 = (const float4*)d_in[1];
    f4*           out4 = (f4*)d_out;
    const int n = in_sizes[0] / 4;   // quaternion is (N,4)

    const int grid = (n + TILE - 1) / TILE;
    gauss_cov_kernel<<<grid, BLOCK, 0, stream>>>(quat, lsc4, out4, n);
}